// Round 5
// baseline (166.339 us; speedup 1.0000x reference)
//
#include <hip/hip_runtime.h>

#define HH 512
#define WW 512
#define NPLANE 48
#define BY 128
#define CHK 16
#define NCH (BY / CHK)   // 8 chunks per block
#define SLOTS 32         // pow2 ring: row r lives at slot r & 31
#define KS 11

typedef __attribute__((ext_vector_type(8))) short short8;   // 8 bf16 (A/B frag)
typedef __attribute__((ext_vector_type(4))) float floatx4;  // 4 fp32 (C/D frag)
typedef __attribute__((ext_vector_type(2))) float float2v;
typedef __attribute__((ext_vector_type(2))) __bf16 bf16x2v;

// exact RNE pack (weights, once)
__device__ inline unsigned pk2bf_rne(float a, float b) {
    union { float f; unsigned u; } ua, ub;
    ua.f = a; ub.f = b;
    unsigned lo = (ua.u + 0x7FFFu + ((ua.u >> 16) & 1u)) >> 16;
    unsigned hi = (ub.u + 0x7FFFu + ((ub.u >> 16) & 1u)) >> 16;
    return lo | (hi << 16);
}

// hot-path pack: float2v -> bf16x2; lowers to v_cvt_pk_bf16_f32 on gfx950
__device__ inline unsigned pkbf2(float2v f) {
    bf16x2v v = __builtin_convertvector(f, bf16x2v);
    return __builtin_bit_cast(unsigned, v);
}

struct Raw { float4 p0, p1, t0, t1; };

// Fully-MFMA SSIM, 4 ring channels: p, t, q=p^2+t^2, pt. Ring = 16384 B.
//
// PAIR-UNROLLED DOUBLE BUFFER, NO ROTATION. Round-4's `C = D; D = load(...)`
// rotation forced the vmcnt wait at the end-of-iteration mov (window ~1 iter
// ~450cy) instead of at the h_step use (2 iters ~900cy = HBM latency) -> waves
// stalled on vmcnt every iteration (VALU 32%, all pipes <35%). Unroll-by-2
// gives each body its own buffer (C=even chunks, D=odd): loads wait only at
// their true use, a full 2 iterations later. Also makes every ring index a
// compile-time constant: vread base == h-write base == 24 (even i) / 8 (odd).
//
// SLOTS=32 exact: vread(i) covers rows 16i-8..16i+23 = the whole 32-slot ring;
// h(i+2) (same iteration, AFTER the reads in program order) overwrites rows
// 16i-8..16i+7 -- precisely the half vread(i) just consumed and vread(i+1)
// no longer needs. In-order per-wave DS makes read-before-write WAR safe.
//
// EPILOGUE IS FIRE-AND-FORGET (rounds 1-2: fused finalize's fence + contended
// same-line RMW held CU slots -> ~130us back-pressure).
//
// launch_bounds(256,6): caps regs at ~85 -> guarantees 6 waves/SIMD = the 6
// resident blocks/CU the 1536-block grid supplies; measured usage was 44, so
// ~40 regs of headroom (round-1's spill was at cap 64 with 9.4MB WRITE_SIZE).
__global__ __launch_bounds__(256, 6) void ssim_kernel(
    const float* __restrict__ pred, const float* __restrict__ target,
    float* __restrict__ ws_sum)
{
    // ring[wave][ch][col][slot], bf16: 4*4*16*32*2 = 16384 B
    __shared__ __align__(16) short ring[4][4][16][SLOTS];

    const int tid = threadIdx.x;
    const int wv = tid >> 6;
    const int lane = tid & 63;
    const int m = lane & 15;     // A-row / B-col / C-col index
    const int quad = lane >> 4;  // k-group / C-row-group

    // Gaussian weights, sigma=1.5
    float wsum = 0.f;
#pragma unroll
    for (int k = 0; k < KS; ++k) {
        float d = (float)(k - 5);
        wsum += __expf(-d * d * (1.0f / 4.5f));
    }
    const float invs = 1.0f / wsum;

    // Banded weight fragment: value at k=quad*8+j is w[k - m - 3] (0 outside band).
    // Serves as B in h-mfma (B[k][n]=w[k-n-3]) and A in v-mfma (A[m][k]=w[k-m-3]).
    short8 Wf;
    {
        union { short8 v; unsigned u[4]; } W;
#pragma unroll
        for (int jj = 0; jj < 4; ++jj) {
            float v0, v1;
            {
                int idx = quad * 8 + 2 * jj - m - 3;
                float d = (float)(idx - 5);
                v0 = (idx >= 0 && idx < KS) ? __expf(-d * d * (1.0f / 4.5f)) * invs : 0.f;
            }
            {
                int idx = quad * 8 + 2 * jj + 1 - m - 3;
                float d = (float)(idx - 5);
                v1 = (idx >= 0 && idx < KS) ? __expf(-d * d * (1.0f / 4.5f)) * invs : 0.f;
            }
            W.u[jj] = pk2bf_rne(v0, v1);
        }
        Wf = W.v;
    }

    const size_t poff = (size_t)blockIdx.z * HH * WW;
    const int X0 = blockIdx.x * 64 + wv * 16;  // wave's 16-col tile
    const int rawX = X0 - 8;                   // 32-col raw window base
    const int Y0 = blockIdx.y * BY;

    // column validity + base pointers are loop-invariant: hoist out of load_raw
    const int c0 = rawX + quad * 8;
    const bool okc0 = (unsigned)c0 < (unsigned)WW;
    const bool okc1 = (unsigned)(c0 + 4) < (unsigned)WW;
    const float* __restrict__ pc = pred + poff + c0;
    const float* __restrict__ tc = target + poff + c0;

    const float2v C1v = {1.0e-4f, 1.0e-4f};
    const float2v C2v = {9.0e-4f, 9.0e-4f};
    float lsum = 0.f;
    const floatx4 z = {0.f, 0.f, 0.f, 0.f};

    // load chunk k's raw rows (zero-padded outside the image)
    auto load_raw = [&](int k) -> Raw {
        Raw r;
        r.p0 = make_float4(0, 0, 0, 0); r.p1 = make_float4(0, 0, 0, 0);
        r.t0 = make_float4(0, 0, 0, 0); r.t1 = make_float4(0, 0, 0, 0);
        const int row = Y0 + CHK * k - 8 + m;
        if ((unsigned)row < (unsigned)HH) {
            const float* pr = pc + (size_t)row * WW;
            const float* tr = tc + (size_t)row * WW;
            if (okc0) { r.p0 = *(const float4*)pr;      r.t0 = *(const float4*)tr; }
            if (okc1) { r.p1 = *(const float4*)(pr + 4); r.t1 = *(const float4*)(tr + 4); }
        }
        return r;
    };

    // h-step: pack raw -> bf16 frags (packed f32 math), 4 MFMA, pack D -> ring
    auto h_step = [&](const Raw& r, int sb) {
        const float2v pa[4] = {{r.p0.x, r.p0.y}, {r.p0.z, r.p0.w},
                               {r.p1.x, r.p1.y}, {r.p1.z, r.p1.w}};
        const float2v tb[4] = {{r.t0.x, r.t0.y}, {r.t0.z, r.t0.w},
                               {r.t1.x, r.t1.y}, {r.t1.z, r.t1.w}};
        union { short8 v; unsigned u[4]; } Fp, Ft, Fq, Fpt;
#pragma unroll
        for (int jj = 0; jj < 4; ++jj) {
            Fp.u[jj]  = pkbf2(pa[jj]);
            Ft.u[jj]  = pkbf2(tb[jj]);
            // q = p^2 + t^2 : packed mul+fma, ONE bf16 quantization
            Fq.u[jj]  = pkbf2(pa[jj] * pa[jj] + tb[jj] * tb[jj]);
            Fpt.u[jj] = pkbf2(pa[jj] * tb[jj]);
        }
        floatx4 Dp  = __builtin_amdgcn_mfma_f32_16x16x32_bf16(Fp.v,  Wf, z, 0, 0, 0);
        floatx4 Dt  = __builtin_amdgcn_mfma_f32_16x16x32_bf16(Ft.v,  Wf, z, 0, 0, 0);
        floatx4 Dq  = __builtin_amdgcn_mfma_f32_16x16x32_bf16(Fq.v,  Wf, z, 0, 0, 0);
        floatx4 Dpt = __builtin_amdgcn_mfma_f32_16x16x32_bf16(Fpt.v, Wf, z, 0, 0, 0);
        // C-layout: col = lane&15 (=m), rows = quad*4 + reg -> slots sb+quad*4+reg
        const int slot = (sb + quad * 4) & (SLOTS - 1);
        uint2 v;
        v.x = pkbf2(float2v{Dp[0],  Dp[1]});  v.y = pkbf2(float2v{Dp[2],  Dp[3]});
        *(uint2*)&ring[wv][0][m][slot] = v;
        v.x = pkbf2(float2v{Dt[0],  Dt[1]});  v.y = pkbf2(float2v{Dt[2],  Dt[3]});
        *(uint2*)&ring[wv][1][m][slot] = v;
        v.x = pkbf2(float2v{Dq[0],  Dq[1]});  v.y = pkbf2(float2v{Dq[2],  Dq[3]});
        *(uint2*)&ring[wv][2][m][slot] = v;
        v.x = pkbf2(float2v{Dpt[0], Dpt[1]}); v.y = pkbf2(float2v{Dpt[2], Dpt[3]});
        *(uint2*)&ring[wv][3][m][slot] = v;
    };

    // v-frag reads (must precede the same-iteration h-write in program order)
    short8 Bp, Bt, Bq, Bpt;
    auto vread = [&](int base) {
        const int sq = (base + quad * 8) & (SLOTS - 1);
        Bp  = *(const short8*)&ring[wv][0][m][sq];
        Bt  = *(const short8*)&ring[wv][1][m][sq];
        Bq  = *(const short8*)&ring[wv][2][m][sq];
        Bpt = *(const short8*)&ring[wv][3][m][sq];
    };

    // v-blur + SSIM (packed f32 pairs)
    auto vfin = [&]() {
        floatx4 Mp  = __builtin_amdgcn_mfma_f32_16x16x32_bf16(Wf, Bp,  z, 0, 0, 0);
        floatx4 Mt  = __builtin_amdgcn_mfma_f32_16x16x32_bf16(Wf, Bt,  z, 0, 0, 0);
        floatx4 Mq  = __builtin_amdgcn_mfma_f32_16x16x32_bf16(Wf, Bq,  z, 0, 0, 0);
        floatx4 Mpt = __builtin_amdgcn_mfma_f32_16x16x32_bf16(Wf, Bpt, z, 0, 0, 0);
#pragma unroll
        for (int h = 0; h < 2; ++h) {
            const float2v mup = {Mp[2*h],  Mp[2*h+1]};
            const float2v mut = {Mt[2*h],  Mt[2*h+1]};
            const float2v mq  = {Mq[2*h],  Mq[2*h+1]};
            const float2v mpt = {Mpt[2*h], Mpt[2*h+1]};
            const float2v mupsq = mup * mup, mutsq = mut * mut, mucr = mup * mut;
            const float2v scr = mpt - mucr;
            const float2v n1 = mucr + mucr + C1v;
            const float2v n2 = scr + scr + C2v;
            const float2v d1 = mupsq + mutsq + C1v;
            const float2v d2 = (mq - mupsq - mutsq) + C2v;   // sp2+st2+C2
            const float2v num = n1 * n2, den = d1 * d2;
            lsum += __fdividef(num[0], den[0]) + __fdividef(num[1], den[1]);
        }
    };

    // Prologue: chunks 0..3 loaded; h(0)->base 24, h(1)->base 8.
    {
        Raw A = load_raw(0);
        Raw B = load_raw(1);
        h_step(A, 24);
        h_step(B, 8);
    }
    Raw C = load_raw(2);   // even-chunk buffer
    Raw D = load_raw(3);   // odd-chunk buffer

    // Main: pairs (i=ii even -> base 24, buffer C; i=ii+1 odd -> base 8, D).
    // Each body: vread -> h_step (overwrite just-read half) -> prefetch own
    // buffer (vmcnt waits 2 iterations later at the next h_step) -> v+SSIM.
#pragma unroll 1
    for (int ii = 0; ii < 6; ii += 2) {
        vread(24);
        h_step(C, 24);              // chunk ii+2
        C = load_raw(ii + 4);       // chunks 4,6,8
        vfin();

        vread(8);
        h_step(D, 8);               // chunk ii+3
        if (ii < 4) D = load_raw(ii + 5);   // chunks 5,7
        vfin();
    }
    // Epilogue pair (ii=6): i=6 with h(8); i=7 with no h-step.
    vread(24);
    h_step(C, 24);                  // chunk 8
    vfin();
    vread(8);
    vfin();

    // wave reduce -> block reduce through the (now dead, wave-private) ring
    // -> ONE fire-and-forget atomic per block. No fence, no return, no counter.
#pragma unroll
    for (int off = 32; off > 0; off >>= 1) lsum += __shfl_down(lsum, off, 64);
    if (lane == 0) *(float*)&ring[wv][0][0][0] = lsum;   // own region only
    __syncthreads();
    if (tid == 0) {
        atomicAdd(ws_sum, *(const float*)&ring[0][0][0][0]
                        + *(const float*)&ring[1][0][0][0]
                        + *(const float*)&ring[2][0][0][0]
                        + *(const float*)&ring[3][0][0][0]);
    }
}

__global__ void finalize_kernel(const float* __restrict__ ws_sum,
                                float* __restrict__ out) {
    out[0] = 1.0f - ws_sum[0] * (1.0f / 12582912.0f);  // N = 16*3*512*512
}

extern "C" void kernel_launch(void* const* d_in, const int* in_sizes, int n_in,
                              void* d_out, int out_size, void* d_ws, size_t ws_size,
                              hipStream_t stream) {
    const float* pred = (const float*)d_in[0];
    const float* target = (const float*)d_in[1];
    float* out = (float*)d_out;
    float* ws = (float*)d_ws;

    hipMemsetAsync(ws, 0, sizeof(float), stream);       // graph-capturable
    dim3 grid(WW / 64, HH / BY, NPLANE);                // 8 x 4 x 48 = 1536 blocks
    ssim_kernel<<<grid, 256, 0, stream>>>(pred, target, ws);
    finalize_kernel<<<1, 1, 0, stream>>>(ws, out);
}

// Round 6
// 142.963 us; speedup vs baseline: 1.1635x; 1.1635x over previous
//
#include <hip/hip_runtime.h>

#define HH 512
#define WW 512
#define NPLANE 48
#define BY 128
#define CHK 16
#define NCH (BY / CHK)   // 8 chunks per block
#define RING 32          // logical ring slots (row r -> slot r & 31)
#define PSTR 40          // physical col stride in shorts: 80 B, 16B-aligned,
                         // proven low-conflict (1.67M); slots 32..39 = pad
#define KS 11

typedef __attribute__((ext_vector_type(8))) short short8;   // 8 bf16 (A/B frag)
typedef __attribute__((ext_vector_type(4))) float floatx4;  // 4 fp32 (C/D frag)
typedef __attribute__((ext_vector_type(2))) float float2v;
typedef __attribute__((ext_vector_type(2))) __bf16 bf16x2v;

// exact RNE pack (weights, once)
__device__ inline unsigned pk2bf_rne(float a, float b) {
    union { float f; unsigned u; } ua, ub;
    ua.f = a; ub.f = b;
    unsigned lo = (ua.u + 0x7FFFu + ((ua.u >> 16) & 1u)) >> 16;
    unsigned hi = (ub.u + 0x7FFFu + ((ub.u >> 16) & 1u)) >> 16;
    return lo | (hi << 16);
}

// hot-path pack: float2v -> bf16x2; lowers to v_cvt_pk_bf16_f32 on gfx950
__device__ inline unsigned pkbf2(float2v f) {
    bf16x2v v = __builtin_convertvector(f, bf16x2v);
    return __builtin_bit_cast(unsigned, v);
}

struct Raw { float4 p0, p1, t0, t1; };

// Fully-MFMA SSIM, 4 ring channels: p, t, q=p^2+t^2, pt.
//
// PAIR-UNROLLED DOUBLE BUFFER, NO ROTATION (round 5): each unrolled body owns
// one Raw buffer (C=even chunks, D=odd); the vmcnt wait lands at the h_step
// use two bodies (~900cy) after issue, covering HBM latency. Round-4's
// `C = D` rotation put the wait one body after issue -> per-iter stalls.
//
// ROUND-5 LESSONS FIXED HERE:
//  * SLOTS=32 pow2 ring shrank the col stride to 64 B -> bank-start (m*16)%32
//    hits 2 banks -> 8-way conflicts (1.67M -> 6.98M, +25us). Physical stride
//    is back to 40 shorts (80 B, 16B-aligned); ring stays LOGICALLY 32 slots
//    (&31 -> compile-time bases 24/8). Pad slots 32..39 are never accessed
//    (reads/writes span bytes [0,64) of each 80 B column).
//  * launch_bounds(256,6) (cap ~84) + predicated `if(ii<4) D=load_raw(...)`
//    spilled both Raw buffers (WRITE_SIZE 48KB -> 45.7MB, FETCH +30MB).
//    Cap back to (256,4)=128 (only proven-no-spill config) and the tail pair
//    is PEELED so every in-loop load is unconditional.
//
// RING=32 WAR correctness (proven, round 5 passed): vread(i) covers rows
// 16i-8..16i+23 = whole ring; h(i+2), after it in program order, overwrites
// rows 16i-8..16i+7 = exactly the half vread(i) just consumed. Per-wave
// in-order DS makes read-before-write safe; ring is wave-private.
//
// EPILOGUE IS FIRE-AND-FORGET (rounds 1-2: fused finalize's fence + contended
// same-line RMW held CU slots -> ~130us back-pressure).
__global__ __launch_bounds__(256, 4) void ssim_kernel(
    const float* __restrict__ pred, const float* __restrict__ target,
    float* __restrict__ ws_sum)
{
    // ring[wave][ch][col][PSTR], bf16: 4*4*16*40*2 = 20480 B
    __shared__ __align__(16) short ring[4][4][16][PSTR];

    const int tid = threadIdx.x;
    const int wv = tid >> 6;
    const int lane = tid & 63;
    const int m = lane & 15;     // A-row / B-col / C-col index
    const int quad = lane >> 4;  // k-group / C-row-group

    // Gaussian weights, sigma=1.5
    float wsum = 0.f;
#pragma unroll
    for (int k = 0; k < KS; ++k) {
        float d = (float)(k - 5);
        wsum += __expf(-d * d * (1.0f / 4.5f));
    }
    const float invs = 1.0f / wsum;

    // Banded weight fragment: value at k=quad*8+j is w[k - m - 3] (0 outside band).
    // Serves as B in h-mfma (B[k][n]=w[k-n-3]) and A in v-mfma (A[m][k]=w[k-m-3]).
    short8 Wf;
    {
        union { short8 v; unsigned u[4]; } W;
#pragma unroll
        for (int jj = 0; jj < 4; ++jj) {
            float v0, v1;
            {
                int idx = quad * 8 + 2 * jj - m - 3;
                float d = (float)(idx - 5);
                v0 = (idx >= 0 && idx < KS) ? __expf(-d * d * (1.0f / 4.5f)) * invs : 0.f;
            }
            {
                int idx = quad * 8 + 2 * jj + 1 - m - 3;
                float d = (float)(idx - 5);
                v1 = (idx >= 0 && idx < KS) ? __expf(-d * d * (1.0f / 4.5f)) * invs : 0.f;
            }
            W.u[jj] = pk2bf_rne(v0, v1);
        }
        Wf = W.v;
    }

    const size_t poff = (size_t)blockIdx.z * HH * WW;
    const int X0 = blockIdx.x * 64 + wv * 16;  // wave's 16-col tile
    const int rawX = X0 - 8;                   // 32-col raw window base
    const int Y0 = blockIdx.y * BY;

    // column validity + base pointers are loop-invariant
    const int c0 = rawX + quad * 8;
    const bool okc0 = (unsigned)c0 < (unsigned)WW;
    const bool okc1 = (unsigned)(c0 + 4) < (unsigned)WW;
    const float* __restrict__ pc = pred + poff + c0;
    const float* __restrict__ tc = target + poff + c0;

    const float2v C1v = {1.0e-4f, 1.0e-4f};
    const float2v C2v = {9.0e-4f, 9.0e-4f};
    float lsum = 0.f;
    const floatx4 z = {0.f, 0.f, 0.f, 0.f};

    // load chunk k's raw rows (zero-padded outside the image)
    auto load_raw = [&](int k) -> Raw {
        Raw r;
        r.p0 = make_float4(0, 0, 0, 0); r.p1 = make_float4(0, 0, 0, 0);
        r.t0 = make_float4(0, 0, 0, 0); r.t1 = make_float4(0, 0, 0, 0);
        const int row = Y0 + CHK * k - 8 + m;
        if ((unsigned)row < (unsigned)HH) {
            const float* pr = pc + (size_t)row * WW;
            const float* tr = tc + (size_t)row * WW;
            if (okc0) { r.p0 = *(const float4*)pr;      r.t0 = *(const float4*)tr; }
            if (okc1) { r.p1 = *(const float4*)(pr + 4); r.t1 = *(const float4*)(tr + 4); }
        }
        return r;
    };

    // h-step: pack raw -> bf16 frags (packed f32 math), 4 MFMA, pack D -> ring
    auto h_step = [&](const Raw& r, int sb) {
        const float2v pa[4] = {{r.p0.x, r.p0.y}, {r.p0.z, r.p0.w},
                               {r.p1.x, r.p1.y}, {r.p1.z, r.p1.w}};
        const float2v tb[4] = {{r.t0.x, r.t0.y}, {r.t0.z, r.t0.w},
                               {r.t1.x, r.t1.y}, {r.t1.z, r.t1.w}};
        union { short8 v; unsigned u[4]; } Fp, Ft, Fq, Fpt;
#pragma unroll
        for (int jj = 0; jj < 4; ++jj) {
            Fp.u[jj]  = pkbf2(pa[jj]);
            Ft.u[jj]  = pkbf2(tb[jj]);
            // q = p^2 + t^2 : packed mul+fma, ONE bf16 quantization
            Fq.u[jj]  = pkbf2(pa[jj] * pa[jj] + tb[jj] * tb[jj]);
            Fpt.u[jj] = pkbf2(pa[jj] * tb[jj]);
        }
        floatx4 Dp  = __builtin_amdgcn_mfma_f32_16x16x32_bf16(Fp.v,  Wf, z, 0, 0, 0);
        floatx4 Dt  = __builtin_amdgcn_mfma_f32_16x16x32_bf16(Ft.v,  Wf, z, 0, 0, 0);
        floatx4 Dq  = __builtin_amdgcn_mfma_f32_16x16x32_bf16(Fq.v,  Wf, z, 0, 0, 0);
        floatx4 Dpt = __builtin_amdgcn_mfma_f32_16x16x32_bf16(Fpt.v, Wf, z, 0, 0, 0);
        // C-layout: col = lane&15 (=m), rows = quad*4 + reg -> slots sb+quad*4+reg
        const int slot = (sb + quad * 4) & (RING - 1);
        uint2 v;
        v.x = pkbf2(float2v{Dp[0],  Dp[1]});  v.y = pkbf2(float2v{Dp[2],  Dp[3]});
        *(uint2*)&ring[wv][0][m][slot] = v;
        v.x = pkbf2(float2v{Dt[0],  Dt[1]});  v.y = pkbf2(float2v{Dt[2],  Dt[3]});
        *(uint2*)&ring[wv][1][m][slot] = v;
        v.x = pkbf2(float2v{Dq[0],  Dq[1]});  v.y = pkbf2(float2v{Dq[2],  Dq[3]});
        *(uint2*)&ring[wv][2][m][slot] = v;
        v.x = pkbf2(float2v{Dpt[0], Dpt[1]}); v.y = pkbf2(float2v{Dpt[2], Dpt[3]});
        *(uint2*)&ring[wv][3][m][slot] = v;
    };

    // v-frag reads (must precede the same-iteration h-write in program order)
    short8 Bp, Bt, Bq, Bpt;
    auto vread = [&](int base) {
        const int sq = (base + quad * 8) & (RING - 1);   // 0/8/16/24: never in pad
        Bp  = *(const short8*)&ring[wv][0][m][sq];
        Bt  = *(const short8*)&ring[wv][1][m][sq];
        Bq  = *(const short8*)&ring[wv][2][m][sq];
        Bpt = *(const short8*)&ring[wv][3][m][sq];
    };

    // v-blur + SSIM (packed f32 pairs)
    auto vfin = [&]() {
        floatx4 Mp  = __builtin_amdgcn_mfma_f32_16x16x32_bf16(Wf, Bp,  z, 0, 0, 0);
        floatx4 Mt  = __builtin_amdgcn_mfma_f32_16x16x32_bf16(Wf, Bt,  z, 0, 0, 0);
        floatx4 Mq  = __builtin_amdgcn_mfma_f32_16x16x32_bf16(Wf, Bq,  z, 0, 0, 0);
        floatx4 Mpt = __builtin_amdgcn_mfma_f32_16x16x32_bf16(Wf, Bpt, z, 0, 0, 0);
#pragma unroll
        for (int h = 0; h < 2; ++h) {
            const float2v mup = {Mp[2*h],  Mp[2*h+1]};
            const float2v mut = {Mt[2*h],  Mt[2*h+1]};
            const float2v mq  = {Mq[2*h],  Mq[2*h+1]};
            const float2v mpt = {Mpt[2*h], Mpt[2*h+1]};
            const float2v mupsq = mup * mup, mutsq = mut * mut, mucr = mup * mut;
            const float2v scr = mpt - mucr;
            const float2v n1 = mucr + mucr + C1v;
            const float2v n2 = scr + scr + C2v;
            const float2v d1 = mupsq + mutsq + C1v;
            const float2v d2 = (mq - mupsq - mutsq) + C2v;   // sp2+st2+C2
            const float2v num = n1 * n2, den = d1 * d2;
            lsum += __fdividef(num[0], den[0]) + __fdividef(num[1], den[1]);
        }
    };

    // Prologue: chunks 0..3 loaded; h(0)->base 24, h(1)->base 8.
    {
        Raw A = load_raw(0);
        Raw B = load_raw(1);
        h_step(A, 24);
        h_step(B, 8);
    }
    Raw C = load_raw(2);   // even-chunk buffer
    Raw D = load_raw(3);   // odd-chunk buffer

    // Main pairs ii=0,2: all loads unconditional (chunks 4..7).
    // Each body: vread -> h_step (overwrites just-read half) -> prefetch own
    // buffer (vmcnt waits 2 bodies later, at its h_step) -> v-MFMA + SSIM.
#pragma unroll 1
    for (int ii = 0; ii < 4; ii += 2) {
        vread(24);
        h_step(C, 24);              // chunk ii+2
        C = load_raw(ii + 4);       // chunks 4, 6
        vfin();

        vread(8);
        h_step(D, 8);               // chunk ii+3
        D = load_raw(ii + 5);       // chunks 5, 7
        vfin();
    }
    // Peeled pair ii=4 (only C reloads: chunk 8 is the last h input).
    vread(24);
    h_step(C, 24);                  // chunk 6
    C = load_raw(8);
    vfin();
    vread(8);
    h_step(D, 8);                   // chunk 7
    vfin();
    // Epilogue pair: i=6 with h(8); i=7 with no h-step.
    vread(24);
    h_step(C, 24);                  // chunk 8
    vfin();
    vread(8);
    vfin();

    // wave reduce -> block reduce through the (now dead, wave-private) ring
    // -> ONE fire-and-forget atomic per block. No fence, no return, no counter.
#pragma unroll
    for (int off = 32; off > 0; off >>= 1) lsum += __shfl_down(lsum, off, 64);
    if (lane == 0) *(float*)&ring[wv][0][0][0] = lsum;   // own region only
    __syncthreads();
    if (tid == 0) {
        atomicAdd(ws_sum, *(const float*)&ring[0][0][0][0]
                        + *(const float*)&ring[1][0][0][0]
                        + *(const float*)&ring[2][0][0][0]
                        + *(const float*)&ring[3][0][0][0]);
    }
}

__global__ void finalize_kernel(const float* __restrict__ ws_sum,
                                float* __restrict__ out) {
    out[0] = 1.0f - ws_sum[0] * (1.0f / 12582912.0f);  // N = 16*3*512*512
}

extern "C" void kernel_launch(void* const* d_in, const int* in_sizes, int n_in,
                              void* d_out, int out_size, void* d_ws, size_t ws_size,
                              hipStream_t stream) {
    const float* pred = (const float*)d_in[0];
    const float* target = (const float*)d_in[1];
    float* out = (float*)d_out;
    float* ws = (float*)d_ws;

    hipMemsetAsync(ws, 0, sizeof(float), stream);       // graph-capturable
    dim3 grid(WW / 64, HH / BY, NPLANE);                // 8 x 4 x 48 = 1536 blocks
    ssim_kernel<<<grid, 256, 0, stream>>>(pred, target, ws);
    finalize_kernel<<<1, 1, 0, stream>>>(ws, out);
}